// Round 8
// baseline (33109.598 us; speedup 1.0000x reference)
//
#include <hip/hip_runtime.h>

#define NHID 512
#define NXW  128
#define TLEN 16384
#define STEPS (TLEN - NXW)      // 16256
#define G    32                 // persistent workgroups
#define B    512                // 8 waves per WG
#define RPW  16                 // hidden rows owned per WG
#define RSLOTS 8                // sync ring depth (32 KB -> IC/L2-hot)

#define FOR4(M)  M(0) M(1) M(2) M(3)
#define FOR16(M) M(0) M(1) M(2) M(3) M(4) M(5) M(6) M(7) \
                 M(8) M(9) M(10) M(11) M(12) M(13) M(14) M(15)

__device__ __forceinline__ float sigmoid_f(float v) { return 1.f / (1.f + __expf(-v)); }
__device__ __forceinline__ float tanh_f(float v)    { return 1.f - 2.f / (1.f + __expf(2.f * v)); }

// wave-uniform broadcast of lane k's hval (SGPR operand into the FMA)
__device__ __forceinline__ float bcast(unsigned hbits, int k) {
    return __uint_as_float(__builtin_amdgcn_readlane(hbits, k));
}

// ---------------------------------------------------------------------------
// R6 skeleton, sync path rebuilt:
//  * 4-deep software-pipelined ring poll (detection ~RT instead of ~2RT)
//  * per-step __syncthreads replaced by LDS release/acquire flags (no vmcnt
//    drain per step; h_hist stores sink freely)
//  * h broadcast via v_readlane (no LDS staging RT before the FMA stretch)
// WG g owns rows [g*16,g*16+16). Wave w polls h-slice [w*64,w*64+64), lane l
// polls exactly element w*64+l of the tag-validated {tag,h} ring.
// ---------------------------------------------------------------------------
__launch_bounds__(B, 2)
__global__ void lstm_persistent(
    const float* x,
    const float* Wf, const float* Uf, const float* bf,
    const float* Wi, const float* Ui, const float* bi,
    const float* Wo, const float* Uo, const float* bo,
    const float* Wc, const float* Uc, const float* bc,
    unsigned long long* ring,     // [RSLOTS][NHID] packed {tag,h}
    float* h_hist)                // [STEPS][NHID] for mu only
{
    __shared__ float x_win[256];        // x ring: refill every 128 steps
    __shared__ float partials[2][B];    // double-buffered across steps
    __shared__ int   flags[8];          // per-wave "partials[t&1] ready" step tags

    const int tid = threadIdx.x;
    const int g   = blockIdx.x;
    const int w   = tid >> 6;            // wave = k-slice 0..7
    const int l   = tid & 63;            // output 0..63
    const int q   = l >> 4;              // gate 0=f 1=i 2=o 3=c
    const int row = g * RPW + (l & 15);

    const float* Utab[4] = {Uf, Ui, Uo, Uc};
    const float* Wtab[4] = {Wf, Wi, Wo, Wc};
    const float* Btab[4] = {bf, bi, bo, bc};

    // weights: 64 U floats + 16 W floats per thread (R6-proven plain pin)
    const float4* Up = (const float4*)(Utab[q] + (size_t)row * NHID + w * 64);
    #define DECLU(i) float4 u##i = Up[i];
    FOR16(DECLU)
    const float4* Wp = (const float4*)(Wtab[q] + row * NXW + w * 16);
    #define DECLW(i) float4 wv##i = Wp[i];
    FOR4(DECLW)
    #define PIN(r) asm volatile("" : "+v"(r.x), "+v"(r.y), "+v"(r.z), "+v"(r.w));
    #define PINU(i) PIN(u##i)
    FOR16(PINU)
    #define PINW(i) PIN(wv##i)
    FOR4(PINW)

    float bias = 0.f, c_prev = 0.f;
    if (w == 0) bias = Btab[q][row];

    // mu-history writer assignment: WG g stores its own 16 rows
    const bool hist_writer = (w == (g >> 2)) && ((l >> 4) == (g & 3));

    if (l == 0) flags[w] = -1;
    __syncthreads();                     // flags valid before first use

    for (int t = 0; t < STEPS; ++t) {
        if ((t & 127) == 0) {            // x window refill (covers x[t..t+255])
            __syncthreads();
            if (tid < 256) {
                int gi = t + tid;
                x_win[tid] = (gi < TLEN) ? x[gi] : 0.f;
            }
            __syncthreads();
        }

        // x-projection partial (independent of h -> overlaps producer latency)
        float xacc = 0.f;
        {
            const int xb = (t & 127) + w * 16;
            #define XF(i) xacc += wv##i.x * x_win[xb + 4*i]     \
                                + wv##i.y * x_win[xb + 4*i + 1] \
                                + wv##i.z * x_win[xb + 4*i + 2] \
                                + wv##i.w * x_win[xb + 4*i + 3];
            FOR4(XF)
        }

        // ---- 4-deep pipelined poll of own ring word of h[t-1] ----
        float hval = 0.f;
        if (t > 0) {
            const unsigned long long* src =
                ring + ((size_t)((t - 1) & (RSLOTS - 1)) << 9) + (w * 64 + l);
            const unsigned want = (unsigned)(t - 1);
            #define RL() __hip_atomic_load(src, __ATOMIC_RELAXED, __HIP_MEMORY_SCOPE_AGENT)
            unsigned long long vv;
            unsigned long long p0 = RL(), p1 = RL(), p2 = RL(), p3 = RL();
            int guard = 0;
            for (;;) {
                if ((unsigned)(p0 >> 32) == want) { vv = p0; break; } p0 = RL();
                if ((unsigned)(p1 >> 32) == want) { vv = p1; break; } p1 = RL();
                if ((unsigned)(p2 >> 32) == want) { vv = p2; break; } p2 = RL();
                if ((unsigned)(p3 >> 32) == want) { vv = p3; break; } p3 = RL();
                if (++guard >= (1 << 14)) {        // bail: wrong answer, not hang
                    vv = (unsigned long long)want << 32; break;
                }
            }
            hval = __uint_as_float((unsigned)vv);
        }
        asm volatile("" ::: "memory");

        // ---- U @ h slice via v_readlane broadcast (no LDS round trip) ----
        float acc = xacc;
        {
            const unsigned hbits = __float_as_uint(hval);
            #define UB(i) { float h0 = bcast(hbits, 4*i);                    \
                            float h1 = bcast(hbits, 4*i + 1);                \
                            float h2 = bcast(hbits, 4*i + 2);                \
                            float h3 = bcast(hbits, 4*i + 3);                \
                            acc += u##i.x * h0 + u##i.y * h1                 \
                                 + u##i.z * h2 + u##i.w * h3; }
            FOR16(UB)
        }

        if (w > 0) {
            partials[t & 1][(w << 6) | l] = acc;
            if (l == 0)   // release: drains this wave's partials ds_writes first
                __hip_atomic_store(&flags[w], t, __ATOMIC_RELEASE,
                                   __HIP_MEMORY_SCOPE_WORKGROUP);
        }

        // mu-history store for step t-1 (sinkable, never forces a drain now)
        if (t > 0 && hist_writer)
            h_hist[(size_t)(t - 1) * NHID + w * 64 + l] = hval;

        // ---- wave-0 tail: LDS-flag wait, reduce, activate, publish ----
        if (w == 0) {
            int gd = 0;
            for (;;) {
                int f1 = __hip_atomic_load(&flags[1], __ATOMIC_RELAXED, __HIP_MEMORY_SCOPE_WORKGROUP);
                int f2 = __hip_atomic_load(&flags[2], __ATOMIC_RELAXED, __HIP_MEMORY_SCOPE_WORKGROUP);
                int f3 = __hip_atomic_load(&flags[3], __ATOMIC_RELAXED, __HIP_MEMORY_SCOPE_WORKGROUP);
                int f4 = __hip_atomic_load(&flags[4], __ATOMIC_RELAXED, __HIP_MEMORY_SCOPE_WORKGROUP);
                int f5 = __hip_atomic_load(&flags[5], __ATOMIC_RELAXED, __HIP_MEMORY_SCOPE_WORKGROUP);
                int f6 = __hip_atomic_load(&flags[6], __ATOMIC_RELAXED, __HIP_MEMORY_SCOPE_WORKGROUP);
                int f7 = __hip_atomic_load(&flags[7], __ATOMIC_RELAXED, __HIP_MEMORY_SCOPE_WORKGROUP);
                if (f1 >= t && f2 >= t && f3 >= t && f4 >= t &&
                    f5 >= t && f6 >= t && f7 >= t) break;
                if (++gd >= (1 << 16)) break;      // bail, don't hang
            }
            asm volatile("" ::: "memory");         // no LDS reads above this line

            const float* p = partials[t & 1];
            float pre = acc + bias;
            #pragma unroll
            for (int s2 = 1; s2 < 8; ++s2) pre += p[s2 * 64 + l];
            float a = (l < 48) ? sigmoid_f(pre) : tanh_f(pre);   // f,i,o / g
            float ai = __shfl(a, l + 16, 64);
            float ao = __shfl(a, l + 32, 64);
            float ag = __shfl(a, l + 48, 64);
            if (l < 16) {
                float c = a * c_prev + ai * ag;
                c_prev = c;
                float h = ao * tanh_f(c);
                unsigned long long pv =
                    ((unsigned long long)(unsigned)t << 32)
                    | (unsigned long long)__float_as_uint(h);
                __hip_atomic_store(
                    ring + ((size_t)(t & (RSLOTS - 1)) << 9) + row, pv,
                    __ATOMIC_RELAXED, __HIP_MEMORY_SCOPE_AGENT);
                if (t == STEPS - 1)                // last h never polled
                    h_hist[(size_t)t * NHID + row] = h;
            }
        }
    }
}

// ---------------------------------------------------------------------------
// epilogue: mu[t] = Ahy . h_hist[t] + by   (one wave per t)
// ---------------------------------------------------------------------------
__global__ void mu_kernel(const float* __restrict__ h_hist,
                          const float* __restrict__ Ahy,
                          const float* __restrict__ by,
                          float* __restrict__ outp, int steps)
{
    int wave = threadIdx.x >> 6;
    int lane = threadIdx.x & 63;
    int t = blockIdx.x * 4 + wave;
    if (t >= steps) return;
    const float* h = h_hist + (size_t)t * NHID;
    float p = 0.f;
    #pragma unroll
    for (int e = 0; e < 8; e++)
        p += Ahy[e * 64 + lane] * h[e * 64 + lane];
    #pragma unroll
    for (int off = 32; off; off >>= 1) p += __shfl_down(p, off, 64);
    if (lane == 0) outp[t] = p + by[0];
}

// ---------------------------------------------------------------------------
extern "C" void kernel_launch(void* const* d_in, const int* in_sizes, int n_in,
                              void* d_out, int out_size, void* d_ws, size_t ws_size,
                              hipStream_t stream)
{
    const float* x  = (const float*)d_in[0];
    const float* Wf = (const float*)d_in[1];
    const float* Uf = (const float*)d_in[2];
    const float* bf = (const float*)d_in[3];
    const float* Wi = (const float*)d_in[4];
    const float* Ui = (const float*)d_in[5];
    const float* bi = (const float*)d_in[6];
    const float* Wo = (const float*)d_in[7];
    const float* Uo = (const float*)d_in[8];
    const float* bo = (const float*)d_in[9];
    const float* Wc = (const float*)d_in[10];
    const float* Uc = (const float*)d_in[11];
    const float* bc = (const float*)d_in[12];
    const float* Ahy = (const float*)d_in[13];
    const float* by  = (const float*)d_in[14];

    unsigned long long* ring = (unsigned long long*)d_ws;        // 32 KB
    float* h_hist = (float*)((char*)d_ws + RSLOTS * NHID * 8);   // ~33.3 MB

    lstm_persistent<<<G, B, 0, stream>>>(x, Wf, Uf, bf, Wi, Ui, bi,
                                         Wo, Uo, bo, Wc, Uc, bc, ring, h_hist);
    int muBlocks = (STEPS + 3) / 4;
    mu_kernel<<<muBlocks, 256, 0, stream>>>(h_hist, Ahy, by, (float*)d_out, STEPS);
}

// Round 9
// 26815.323 us; speedup vs baseline: 1.2347x; 1.2347x over previous
//
#include <hip/hip_runtime.h>

#define NHID 512
#define NXW  128
#define TLEN 16384
#define STEPS (TLEN - NXW)      // 16256
#define G    32                 // persistent workgroups
#define B    512                // 8 waves per WG
#define RPW  16                 // hidden rows owned per WG
#define RSLOTS 8                // sync ring depth (32 KB -> IC/L2-hot)

#define FOR4(M)  M(0) M(1) M(2) M(3)
#define FOR16(M) M(0) M(1) M(2) M(3) M(4) M(5) M(6) M(7) \
                 M(8) M(9) M(10) M(11) M(12) M(13) M(14) M(15)

__device__ __forceinline__ float sigmoid_f(float v) { return 1.f / (1.f + __expf(-v)); }
__device__ __forceinline__ float tanh_f(float v)    { return 1.f - 2.f / (1.f + __expf(2.f * v)); }

// ---------------------------------------------------------------------------
// R6 core (best so far: 25.6 ms) + s_sleep poll backoff.
// WG g owns rows [g*16, g*16+16). 8 waves = 8 k-slices of 64.
// Lane l = output (gate q=l>>4, row g*16+(l&15)); wave w polls h-slice
// [w*64, w*64+64) of the hot ring (tag-validated {tag,h} 8B words).
// Ring slot reuse race-free (tags t-1 observed => all WGs finished t-1).
// Poll backoff: s_sleep(1) (~64cy) after each miss — 16K threads hammering
// 32 ring lines also delays the producers' stores into those lines (R6-R8
// dispatch variance evidence); throttling the pollers shortens the
// store->visible leg at <=64cy detection cost.
// ---------------------------------------------------------------------------
__launch_bounds__(B, 2)
__global__ void lstm_persistent(
    const float* x,
    const float* Wf, const float* Uf, const float* bf,
    const float* Wi, const float* Ui, const float* bi,
    const float* Wo, const float* Uo, const float* bo,
    const float* Wc, const float* Uc, const float* bc,
    unsigned long long* ring,     // [RSLOTS][NHID] packed {tag,h}
    float* h_hist)                // [STEPS][NHID] for mu only
{
    __shared__ float x_win[256];                    // x ring: refill every 128 steps
    __shared__ __align__(16) float h_buf[8][64];    // per-wave h-slice staging
    __shared__ float partials[2][B];                // double-buffered

    const int tid = threadIdx.x;
    const int g   = blockIdx.x;
    const int w   = tid >> 6;            // wave = k-slice 0..7
    const int l   = tid & 63;            // output 0..63
    const int q   = l >> 4;              // gate 0=f 1=i 2=o 3=c
    const int row = g * RPW + (l & 15);

    const float* Utab[4] = {Uf, Ui, Uo, Uc};
    const float* Wtab[4] = {Wf, Wi, Wo, Wc};
    const float* Btab[4] = {bf, bi, bo, bc};

    // load + pin weights: 64 U floats + 16 W floats per thread (R3/R6-proven)
    const float4* Up = (const float4*)(Utab[q] + (size_t)row * NHID + w * 64);
    #define DECLU(i) float4 u##i = Up[i];
    FOR16(DECLU)
    const float4* Wp = (const float4*)(Wtab[q] + row * NXW + w * 16);
    #define DECLW(i) float4 wv##i = Wp[i];
    FOR4(DECLW)
    #define PIN(r) asm volatile("" : "+v"(r.x), "+v"(r.y), "+v"(r.z), "+v"(r.w));
    #define PINU(i) PIN(u##i)
    FOR16(PINU)
    #define PINW(i) PIN(wv##i)
    FOR4(PINW)

    float bias = 0.f, c_prev = 0.f;
    if (w == 0) bias = Btab[q][row];

    // mu-history writer: WG g stores its own 16 rows from its polled values
    const bool hist_writer = (w == (g >> 2)) && ((l >> 4) == (g & 3));

    h_buf[w][l] = 0.f;                   // h[-1] = 0 (own wave reads only)

    for (int t = 0; t < STEPS; ++t) {
        if ((t & 127) == 0) {            // x window refill (covers x[t..t+255])
            __syncthreads();
            if (tid < 256) {
                int gi = t + tid;
                x_win[tid] = (gi < TLEN) ? x[gi] : 0.f;
            }
            __syncthreads();
        }

        // x-projection partial (independent of h -> overlaps producer latency)
        float xacc = 0.f;
        {
            const int xb = (t & 127) + w * 16;
            #define XF(i) xacc += wv##i.x * x_win[xb + 4*i]     \
                                + wv##i.y * x_win[xb + 4*i + 1] \
                                + wv##i.z * x_win[xb + 4*i + 2] \
                                + wv##i.w * x_win[xb + 4*i + 3];
            FOR4(XF)
        }

        // poll own 8B ring word of h[t-1]: tag-validated, sleep-backoff
        float hval = 0.f;
        if (t > 0) {
            const unsigned long long* src =
                ring + ((size_t)((t - 1) & (RSLOTS - 1)) << 9) + (w * 64 + l);
            const unsigned want = (unsigned)(t - 1);
            unsigned long long vv; int guard = 0;
            for (;;) {
                vv = __hip_atomic_load(src, __ATOMIC_RELAXED, __HIP_MEMORY_SCOPE_AGENT);
                if ((unsigned)(vv >> 32) == want) break;
                __builtin_amdgcn_s_sleep(1);          // ~64cy: de-crowd the fabric
                if (++guard >= (1 << 17)) {           // bail: wrong, not hung
                    vv = (unsigned long long)want << 32; break;
                }
            }
            hval = __uint_as_float((unsigned)vv);
            h_buf[w][l] = hval;
        }

        // U @ h slice: 64 FMA vs wave-uniform LDS broadcast reads
        float acc = xacc;
        const float4* hb4 = (const float4*)h_buf[w];
        #define UF(i) { float4 hv = hb4[i];                       \
                        acc += u##i.x * hv.x + u##i.y * hv.y      \
                             + u##i.z * hv.z + u##i.w * hv.w; }
        FOR16(UF)
        partials[t & 1][(w << 6) | l] = acc;

        // mu-history store for step t-1 (off the critical path, sinkable)
        if (t > 0 && hist_writer)
            h_hist[(size_t)(t - 1) * NHID + w * 64 + l] = hval;

        __syncthreads();                 // the ONE per-step barrier

        // wave-0 tail: reduce 8 k-slices, activate, combine, publish to ring
        if (w == 0) {
            const float* p = partials[t & 1];
            float pre = acc + bias;
            #pragma unroll
            for (int s2 = 1; s2 < 8; ++s2) pre += p[s2 * 64 + l];
            float a = (l < 48) ? sigmoid_f(pre) : tanh_f(pre);   // f,i,o / g
            float ai = __shfl(a, l + 16, 64);
            float ao = __shfl(a, l + 32, 64);
            float ag = __shfl(a, l + 48, 64);
            if (l < 16) {
                float c = a * c_prev + ai * ag;
                c_prev = c;
                float h = ao * tanh_f(c);
                unsigned long long pv =
                    ((unsigned long long)(unsigned)t << 32)
                    | (unsigned long long)__float_as_uint(h);
                __hip_atomic_store(
                    ring + ((size_t)(t & (RSLOTS - 1)) << 9) + row, pv,
                    __ATOMIC_RELAXED, __HIP_MEMORY_SCOPE_AGENT);
                if (t == STEPS - 1)      // last h is never polled: store direct
                    h_hist[(size_t)t * NHID + row] = h;
            }
        }
    }
}

// ---------------------------------------------------------------------------
// epilogue: mu[t] = Ahy . h_hist[t] + by   (one wave per t)
// ---------------------------------------------------------------------------
__global__ void mu_kernel(const float* __restrict__ h_hist,
                          const float* __restrict__ Ahy,
                          const float* __restrict__ by,
                          float* __restrict__ outp, int steps)
{
    int wave = threadIdx.x >> 6;
    int lane = threadIdx.x & 63;
    int t = blockIdx.x * 4 + wave;
    if (t >= steps) return;
    const float* h = h_hist + (size_t)t * NHID;
    float p = 0.f;
    #pragma unroll
    for (int e = 0; e < 8; e++)
        p += Ahy[e * 64 + lane] * h[e * 64 + lane];
    #pragma unroll
    for (int off = 32; off; off >>= 1) p += __shfl_down(p, off, 64);
    if (lane == 0) outp[t] = p + by[0];
}

// ---------------------------------------------------------------------------
extern "C" void kernel_launch(void* const* d_in, const int* in_sizes, int n_in,
                              void* d_out, int out_size, void* d_ws, size_t ws_size,
                              hipStream_t stream)
{
    const float* x  = (const float*)d_in[0];
    const float* Wf = (const float*)d_in[1];
    const float* Uf = (const float*)d_in[2];
    const float* bf = (const float*)d_in[3];
    const float* Wi = (const float*)d_in[4];
    const float* Ui = (const float*)d_in[5];
    const float* bi = (const float*)d_in[6];
    const float* Wo = (const float*)d_in[7];
    const float* Uo = (const float*)d_in[8];
    const float* bo = (const float*)d_in[9];
    const float* Wc = (const float*)d_in[10];
    const float* Uc = (const float*)d_in[11];
    const float* bc = (const float*)d_in[12];
    const float* Ahy = (const float*)d_in[13];
    const float* by  = (const float*)d_in[14];

    unsigned long long* ring = (unsigned long long*)d_ws;        // 32 KB
    float* h_hist = (float*)((char*)d_ws + RSLOTS * NHID * 8);   // ~33.3 MB

    lstm_persistent<<<G, B, 0, stream>>>(x, Wf, Uf, bf, Wi, Ui, bi,
                                         Wo, Uo, bo, Wc, Uc, bc, ring, h_hist);
    int muBlocks = (STEPS + 3) / 4;
    mu_kernel<<<muBlocks, 256, 0, stream>>>(h_hist, Ahy, by, (float*)d_out, STEPS);
}